// Round 15
// baseline (178.841 us; speedup 1.0000x reference)
//
#include <hip/hip_runtime.h>
#include <hip/hip_bf16.h>

// TrajGRU cell, B=8, Cin=8, Ch=64, H=W=128, L=5. Inputs f32, OUTPUT f32.
//   k_transpose      : cat_T[b][p][96] bf16 (h 0-63, x 64-71, pad) ; x_T[b][p][32]
//   k_prep_all       : all 4 weight packs in one launch
//   k_flowgen_mfma   : f_T = tanh(25-tap implicit GEMM, K=96); LDS-staged
//   k_flows_mfma     : flows = 25-tap implicit GEMM, K=32           f32
//   k_warp_gemm_gate : 32-px tile (LDS 20,480B -> 8 blocks/CU, 100% occupancy);
//                      bilinear-warp into XOR-swizzled LDS, i2h MFMA overlaps
//                      barrier, h2h GEMM from LDS, GRU gate -> f32
//   BATCH-PER-XCD: heavy kernels 1D grid, b = id & 7 (validated R12: FETCH
//   145->38 MB)
//
// ws layout:
//   [0)          catT  25,165,824
//   [25,165,824) f_T    8,388,608
//   [33,554,432) flows  5,242,880
//   [38,797,312) xT     8,388,608
//   [63,963,136) packed_ret 122,880
//   [64,086,016) pfg 153,600 | [64,239,616) pfl 25,600 | [64,265,216) pih 110,592
//   end 64,375,808  (proven ws_size >= 134,340,608)

#define HW 16384
#define W_ 128

typedef __attribute__((ext_vector_type(8))) short short8;
typedef __attribute__((ext_vector_type(4))) float f32x4;
typedef __attribute__((ext_vector_type(4))) unsigned int u32x4;

__device__ __forceinline__ float sigmoidf_(float z) { return 1.f / (1.f + expf(-z)); }

__device__ __forceinline__ short bf16bits(float v) {
  __hip_bfloat16 bv = __float2bfloat16(v);
  return (short)*reinterpret_cast<unsigned short*>(&bv);
}
__device__ __forceinline__ unsigned int bf16u(float v) {
  __hip_bfloat16 bv = __float2bfloat16(v);
  return (unsigned int)*reinterpret_cast<unsigned short*>(&bv);
}
__device__ __forceinline__ float bfb2f(short s) {
  union { unsigned int u; float f; } cv;
  cv.u = ((unsigned int)(unsigned short)s) << 16;
  return cv.f;
}

// ---- cat_T[b][p][96] (h,x,0) + x_T[b][p][32] (x,0)
__global__ __launch_bounds__(256) void k_transpose(
    const float* __restrict__ h, const float* __restrict__ x,
    __hip_bfloat16* __restrict__ cat, __hip_bfloat16* __restrict__ xT) {
  const int b = blockIdx.y;
  const int wv = threadIdx.x >> 6, l = threadIdx.x & 63;
  const int p = blockIdx.x * 64 + l;
  const int c0 = wv * 24;
  short8 v[3];
#pragma unroll
  for (int q = 0; q < 3; ++q)
#pragma unroll
    for (int k = 0; k < 8; ++k) {
      int c = c0 + q * 8 + k;
      float val = 0.f;
      if (c < 64)      val = h[((size_t)(b * 64 + c) << 14) + p];
      else if (c < 72) val = x[((size_t)(b * 8 + (c - 64)) << 14) + p];
      v[q][k] = bf16bits(val);
    }
  short8* dst = reinterpret_cast<short8*>(cat + ((size_t)b * HW + p) * 96 + c0);
#pragma unroll
  for (int q = 0; q < 3; ++q) dst[q] = v[q];

  short8 xv;
#pragma unroll
  for (int k = 0; k < 8; ++k)
    xv[k] = (wv == 0) ? bf16bits(x[((size_t)(b * 8 + k) << 14) + p]) : (short)0;
  reinterpret_cast<short8*>(xT + ((size_t)b * HW + p) * 32)[wv] = xv;
}

// ---- all weight preps fused (ranges: fg 76800 | fl 12800 | ret 61440 | ih 55296)
__global__ void k_prep_all(const float* __restrict__ w_i2f,
                           const float* __restrict__ w_h2f,
                           const float* __restrict__ w_flows,
                           const float* __restrict__ w_ret,
                           const float* __restrict__ w_i2h,
                           __hip_bfloat16* __restrict__ pfg,
                           __hip_bfloat16* __restrict__ pfl,
                           __hip_bfloat16* __restrict__ packed,
                           __hip_bfloat16* __restrict__ pih) {
  int t = blockIdx.x * 256 + threadIdx.x;
  if (t < 76800) {
    int i = t & 7, l = (t >> 3) & 63, ot = (t >> 9) & 1, r = t >> 10;
    int ks = r % 3, tap = r / 3;
    int oc = ot * 16 + (l & 15), k = ks * 32 + ((l >> 4) << 3) + i;
    float v = 0.f;
    if (k < 64)      v = w_h2f[(size_t)(oc * 64 + k) * 25 + tap];
    else if (k < 72) v = w_i2f[(size_t)(oc * 8 + (k - 64)) * 25 + tap];
    pfg[t] = __float2bfloat16(v);
    return;
  }
  t -= 76800;
  if (t < 12800) {
    int i = t & 7, l = (t >> 3) & 63, tap = t >> 9;
    int oc = l & 15, k = ((l >> 4) << 3) + i;
    pfl[t] = __float2bfloat16(oc < 10 ? w_flows[(size_t)(oc * 32 + k) * 25 + tap] : 0.f);
    return;
  }
  t -= 12800;
  if (t < 61440) {
    int i = t & 7, l = (t >> 3) & 63, ks = (t >> 9) % 10, mt = t / 5120;
    int m = mt * 16 + (l & 15), k = ks * 32 + ((l >> 4) << 3) + i;
    packed[t] = __float2bfloat16(w_ret[(size_t)m * 320 + k]);
    return;
  }
  t -= 61440;
  if (t < 55296) {
    int i = t & 7, l = (t >> 3) & 63, mt = (t >> 9) % 12, tap = t / 6144;
    int m = mt * 16 + (l & 15), k = ((l >> 4) << 3) + i;
    pih[t] = __float2bfloat16(k < 8 ? w_i2h[(size_t)(m * 8 + k) * 9 + tap] : 0.f);
  }
}

// ---- flowgen: 25-tap implicit GEMM, K=96 (3 staged k-slices). Batch = id&7.
__global__ __launch_bounds__(256) void k_flowgen_mfma(
    const __hip_bfloat16* __restrict__ cat, const __hip_bfloat16* __restrict__ pfg,
    const float* __restrict__ b_i2f, const float* __restrict__ b_h2f,
    __hip_bfloat16* __restrict__ f_T) {
  const int id = blockIdx.x;
  const int b = id & 7, r0 = id >> 3;
  const int y = r0 >> 1, x0 = (r0 & 1) << 6;
  const int wv = threadIdx.x >> 6, l = threadIdx.x & 63;
  const int lr = l & 15, lq = l >> 4;
  const int xa = x0 + wv * 16 + lr;
  const short8* pf = reinterpret_cast<const short8*>(pfg);
  const short8 z8 = {0, 0, 0, 0, 0, 0, 0, 0};

  __shared__ unsigned int s[5 * 68 * 20];  // 27,200 B

  f32x4 acc[2] = {{0.f, 0.f, 0.f, 0.f}, {0.f, 0.f, 0.f, 0.f}};

  for (int ks = 0; ks < 3; ++ks) {
    __syncthreads();
    for (int c = threadIdx.x; c < 1360; c += 256) {
      int px = c >> 2, part = c & 3;
      int r = px / 68, cc = px - r * 68;
      int gy = min(max(y + r - 2, 0), 127);
      int gx = min(max(x0 + cc - 2, 0), 127);
      u32x4 v = *reinterpret_cast<const u32x4*>(
          cat + ((size_t)b * HW + gy * W_ + gx) * 96 + ks * 32 + part * 8);
      *reinterpret_cast<u32x4*>(s + (r * 68 + cc) * 20 + part * 4) = v;
    }
    __syncthreads();
#pragma unroll
    for (int tap = 0; tap < 25; ++tap) {
      const int dy = tap / 5 - 2, dx = tap % 5 - 2;
      const int yy = y + dy, xx = xa + dx;
      const bool ok = ((unsigned)yy < 128u) && ((unsigned)xx < 128u);
      const int cidx = wv * 16 + lr + dx + 2;
      union { u32x4 u; short8 s8; } cv;
      cv.u = *reinterpret_cast<const u32x4*>(s + ((dy + 2) * 68 + cidx) * 20 + lq * 4);
      short8 af = ok ? cv.s8 : z8;
#pragma unroll
      for (int ot = 0; ot < 2; ++ot) {
        short8 bf = pf[(size_t)(((tap * 3 + ks) << 1) + ot) * 64 + l];
        acc[ot] = __builtin_amdgcn_mfma_f32_16x16x32_bf16(af, bf, acc[ot], 0, 0, 0);
      }
    }
  }

  const int pbase = y * W_ + x0 + wv * 16 + lq * 4;
#pragma unroll
  for (int ot = 0; ot < 2; ++ot) {
    const int oc = ot * 16 + lr;
    const float bias = b_i2f[oc] + b_h2f[oc];
#pragma unroll
    for (int r = 0; r < 4; ++r)
      f_T[((size_t)b * HW + pbase + r) * 32 + oc] =
          __float2bfloat16(tanhf(acc[ot][r] + bias));
  }
}

// ---- flows: 25-tap implicit GEMM, K=32. Batch = id&7 (same XCD as producer).
__global__ __launch_bounds__(256) void k_flows_mfma(
    const __hip_bfloat16* __restrict__ f_T, const __hip_bfloat16* __restrict__ pfl,
    const float* __restrict__ b_flows, float* __restrict__ flows) {
  const int id = blockIdx.x;
  const int b = id & 7, r0 = id >> 3;
  const int y = r0 >> 1, x0 = (r0 & 1) << 6;
  const int wv = threadIdx.x >> 6, l = threadIdx.x & 63;
  const int lr = l & 15, lq = l >> 4;
  const int xa = x0 + wv * 16 + lr;
  const short8* ft8 = reinterpret_cast<const short8*>(f_T + (size_t)b * HW * 32);
  const short8* pf = reinterpret_cast<const short8*>(pfl);
  const short8 z8 = {0, 0, 0, 0, 0, 0, 0, 0};

  f32x4 acc = {0.f, 0.f, 0.f, 0.f};

#pragma unroll
  for (int tap = 0; tap < 25; ++tap) {
    const int dy = tap / 5 - 2, dx = tap % 5 - 2;
    const int yy = y + dy, xx = xa + dx;
    const bool ok = ((unsigned)yy < 128u) && ((unsigned)xx < 128u);
    const int yc = min(max(yy, 0), 127), xc = min(max(xx, 0), 127);
    short8 araw = ft8[(size_t)(yc * W_ + xc) * 4 + lq];
    short8 af = ok ? araw : z8;
    short8 bf = pf[tap * 64 + l];
    acc = __builtin_amdgcn_mfma_f32_16x16x32_bf16(af, bf, acc, 0, 0, 0);
  }

  if (lr < 10) {
    const float bb = b_flows[lr];
    const int p = y * W_ + x0 + wv * 16 + lq * 4;
    f32x4 v = {acc[0] + bb, acc[1] + bb, acc[2] + bb, acc[3] + bb};
    *reinterpret_cast<f32x4*>(flows + ((size_t)(b * 10 + lr) << 14) + p) = v;
  }
}

// ---- FUSED warp + h2h GEMM + i2h + gating. 32-px tile, 8 blocks/CU.
// Phase 1: lane = (sub = l>>3 -> pixel, c8 = l&7 -> channel octet); one pass
// covers 4 waves x 8 px = 32 px. Grouped loads (all flows, all 20 corners).
// Phase 2: pt in {0,1}; h2h GEMM A from swizzled LDS; i2h pre-barrier.
__global__ __launch_bounds__(256, 4) void k_warp_gemm_gate(
    const __hip_bfloat16* __restrict__ cat, const float* __restrict__ flows,
    const __hip_bfloat16* __restrict__ packed,
    const __hip_bfloat16* __restrict__ pih,
    const __hip_bfloat16* __restrict__ xT,
    const float* __restrict__ h,
    const float* __restrict__ b_i2h, const float* __restrict__ b_ret,
    float* __restrict__ out) {
  const int id = blockIdx.x;
  const int b = id & 7;
  const int p0 = (id >> 3) << 5;  // 32-px tile
  const int t = threadIdx.x;
  const int wv = t >> 6, l = t & 63;

  __shared__ unsigned int lds[32 * 160];  // 20,480 B -> 8 blocks/CU

  {  // phase 1: channel-octet gather with grouped loads
    const int sub = l >> 3, c8 = l & 7;
    const __hip_bfloat16* cbase = cat + (size_t)b * HW * 96 + c8 * 8;
    const int pxl = wv * 8 + sub;  // 0..31
    const int p = p0 + pxl;
    const int ox = p & 127, oy = p >> 7;
    const unsigned int sw = (unsigned)(pxl & 7);

    float fx[5], fy[5];
#pragma unroll
    for (int fl = 0; fl < 5; ++fl) {
      fx[fl] = flows[((size_t)(b * 10 + 2 * fl) << 14) + p];
      fy[fl] = flows[((size_t)(b * 10 + 2 * fl + 1) << 14) + p];
    }
    float w00[5], w01[5], w10[5], w11[5];
    const short8 *q00[5], *q01[5], *q10[5], *q11[5];
#pragma unroll
    for (int fl = 0; fl < 5; ++fl) {
      float px = fminf(fmaxf((float)ox - fx[fl], 0.f), 127.f);
      float py = fminf(fmaxf((float)oy - fy[fl], 0.f), 127.f);
      float x0f = floorf(px), y0f = floorf(py);
      float wx = px - x0f, wy = py - y0f;
      int x0 = (int)x0f, y0 = (int)y0f;
      int x1 = min(x0 + 1, 127), y1 = min(y0 + 1, 127);
      w00[fl] = (1.f - wx) * (1.f - wy); w01[fl] = wx * (1.f - wy);
      w10[fl] = (1.f - wx) * wy;         w11[fl] = wx * wy;
      q00[fl] = reinterpret_cast<const short8*>(cbase + (size_t)(y0 * W_ + x0) * 96);
      q01[fl] = reinterpret_cast<const short8*>(cbase + (size_t)(y0 * W_ + x1) * 96);
      q10[fl] = reinterpret_cast<const short8*>(cbase + (size_t)(y1 * W_ + x0) * 96);
      q11[fl] = reinterpret_cast<const short8*>(cbase + (size_t)(y1 * W_ + x1) * 96);
    }
    short8 v00[5], v01[5], v10[5], v11[5];
#pragma unroll
    for (int fl = 0; fl < 5; ++fl) {
      v00[fl] = *q00[fl]; v01[fl] = *q01[fl];
      v10[fl] = *q10[fl]; v11[fl] = *q11[fl];
    }
#pragma unroll
    for (int fl = 0; fl < 5; ++fl) {
      u32x4 wvv;
#pragma unroll
      for (int kk = 0; kk < 4; ++kk) {
        float a0 = bfb2f(v00[fl][2 * kk]) * w00[fl] + bfb2f(v01[fl][2 * kk]) * w01[fl]
                 + bfb2f(v10[fl][2 * kk]) * w10[fl] + bfb2f(v11[fl][2 * kk]) * w11[fl];
        float a1 = bfb2f(v00[fl][2 * kk + 1]) * w00[fl] + bfb2f(v01[fl][2 * kk + 1]) * w01[fl]
                 + bfb2f(v10[fl][2 * kk + 1]) * w10[fl] + bfb2f(v11[fl][2 * kk + 1]) * w11[fl];
        wvv[kk] = bf16u(a0) | (bf16u(a1) << 16);
      }
      const int g0 = fl * 8 + c8;  // 16B chunk index (0..39)
      *reinterpret_cast<u32x4*>(lds + pxl * 160 + ((unsigned)(g0 ^ sw) << 2)) = wvv;
    }
  }

  // i2h: 9-tap implicit GEMM over x_T (no LDS use — overlaps the barrier wait)
  const int y = p0 >> 7, x0 = p0 & 127;
  const int lr = l & 15, lq = l >> 4;

  f32x4 acc[3][2], accm[2];
#pragma unroll
  for (int g = 0; g < 3; ++g)
#pragma unroll
    for (int q = 0; q < 2; ++q) acc[g][q] = {0.f, 0.f, 0.f, 0.f};
#pragma unroll
  for (int q = 0; q < 2; ++q) accm[q] = {0.f, 0.f, 0.f, 0.f};

  {
    const short8* xb = reinterpret_cast<const short8*>(xT + (size_t)b * HW * 32);
    const short8* pi = reinterpret_cast<const short8*>(pih);
    const short8 z8 = {0, 0, 0, 0, 0, 0, 0, 0};
#pragma unroll
    for (int tap = 0; tap < 9; ++tap) {
      const int dy = tap / 3 - 1, dx = tap % 3 - 1;
      const int yy = y + dy;
      const bool yok = (unsigned)yy < 128u;
      const int ycl = min(max(yy, 0), 127);
      short8 bf[3];
#pragma unroll
      for (int g = 0; g < 3; ++g) bf[g] = pi[(size_t)(tap * 12 + g * 4 + wv) * 64 + l];
#pragma unroll
      for (int pt = 0; pt < 2; ++pt) {
        const int xx = x0 + pt * 16 + lr + dx;
        const bool ok = yok && ((unsigned)xx < 128u);
        const int xcl = min(max(xx, 0), 127);
        short8 araw = xb[(size_t)(ycl * W_ + xcl) * 4 + lq];
        short8 af = ok ? araw : z8;
        acc[0][pt] = __builtin_amdgcn_mfma_f32_16x16x32_bf16(af, bf[0], acc[0][pt], 0, 0, 0);
        acc[1][pt] = __builtin_amdgcn_mfma_f32_16x16x32_bf16(af, bf[1], acc[1][pt], 0, 0, 0);
        accm[pt]   = __builtin_amdgcn_mfma_f32_16x16x32_bf16(af, bf[2], accm[pt], 0, 0, 0);
      }
    }
  }

  __syncthreads();

  // h2h GEMM: A-fragments from swizzled LDS
  const short8* bp0 = reinterpret_cast<const short8*>(packed) + (size_t)wv * 640 + l;
  for (int ks = 0; ks < 10; ++ks) {
    short8 af[2];
#pragma unroll
    for (int pt = 0; pt < 2; ++pt) {
      const int row = pt * 16 + lr;
      union { u32x4 u; short8 s; } cv;
      cv.u = *reinterpret_cast<const u32x4*>(
          lds + row * 160 + ((unsigned)(((ks << 2) + lq) ^ (row & 7)) << 2));
      af[pt] = cv.s;
    }
    short8 bf[3];
#pragma unroll
    for (int g = 0; g < 3; ++g) bf[g] = bp0[g * 2560 + ks * 64];
#pragma unroll
    for (int g = 0; g < 3; ++g)
#pragma unroll
      for (int pt = 0; pt < 2; ++pt)
        acc[g][pt] = __builtin_amdgcn_mfma_f32_16x16x32_bf16(af[pt], bf[g],
                                                             acc[g][pt], 0, 0, 0);
  }

  const int c = wv * 16 + lr;
  const float bir = b_i2h[c], biu = b_i2h[64 + c], bim = b_i2h[128 + c];
  const float brr = b_ret[c], bru = b_ret[64 + c], brm = b_ret[128 + c];
  const float* hb = h + ((size_t)(b * 64 + c) << 14);
  float* ob = out + ((size_t)(b * 64 + c) << 14);
#pragma unroll
  for (int pt = 0; pt < 2; ++pt) {
#pragma unroll
    for (int r = 0; r < 4; ++r) {
      const int pixel = p0 + pt * 16 + lq * 4 + r;
      float rg = sigmoidf_(acc[0][pt][r] + bir + brr);
      float ug = sigmoidf_(acc[1][pt][r] + biu + bru);
      float mg = tanhf((accm[pt][r] + bim) + rg * (acc[2][pt][r] + brm));
      ob[pixel] = ug * hb[pixel] + (1.f - ug) * mg;
    }
  }
}

extern "C" void kernel_launch(void* const* d_in, const int* in_sizes, int n_in,
                              void* d_out, int out_size, void* d_ws, size_t ws_size,
                              hipStream_t stream) {
  const float* x       = (const float*)d_in[0];
  const float* h       = (const float*)d_in[1];
  const float* w_i2f   = (const float*)d_in[2];
  const float* b_i2f   = (const float*)d_in[3];
  const float* w_h2f   = (const float*)d_in[4];
  const float* b_h2f   = (const float*)d_in[5];
  const float* w_flows = (const float*)d_in[6];
  const float* b_flows = (const float*)d_in[7];
  const float* w_i2h   = (const float*)d_in[8];
  const float* b_i2h   = (const float*)d_in[9];
  const float* w_ret   = (const float*)d_in[10];
  const float* b_ret   = (const float*)d_in[11];
  float* out           = (float*)d_out;
  char* ws = (char*)d_ws;

  __hip_bfloat16* catT   = (__hip_bfloat16*)(ws);             // 25,165,824
  __hip_bfloat16* f_T    = (__hip_bfloat16*)(ws + 25165824);  // 8,388,608
  float* flows           = (float*)(ws + 33554432);           // 5,242,880
  __hip_bfloat16* xT     = (__hip_bfloat16*)(ws + 38797312);  // 8,388,608
  __hip_bfloat16* packed = (__hip_bfloat16*)(ws + 63963136);  // 122,880
  __hip_bfloat16* pfg    = (__hip_bfloat16*)(ws + 64086016);  // 153,600
  __hip_bfloat16* pfl    = (__hip_bfloat16*)(ws + 64239616);  // 25,600
  __hip_bfloat16* pih    = (__hip_bfloat16*)(ws + 64265216);  // 110,592

  k_transpose<<<dim3(256, 8), 256, 0, stream>>>(h, x, catT, xT);
  k_prep_all<<<806, 256, 0, stream>>>(w_i2f, w_h2f, w_flows, w_ret, w_i2h,
                                      pfg, pfl, packed, pih);

  k_flowgen_mfma<<<2048, 256, 0, stream>>>(catT, pfg, b_i2f, b_h2f, f_T);
  k_flows_mfma<<<2048, 256, 0, stream>>>(f_T, pfl, b_flows, flows);

  k_warp_gemm_gate<<<4096, 256, 0, stream>>>(catT, flows, packed, pih, xT,
                                             h, b_i2h, b_ret, out);
}

// Round 16
// 178.501 us; speedup vs baseline: 1.0019x; 1.0019x over previous
//
#include <hip/hip_runtime.h>
#include <hip/hip_bf16.h>

// TrajGRU cell, B=8, Cin=8, Ch=64, H=W=128, L=5. Inputs f32, OUTPUT f32.
//   k_transpose      : cat_T[b][p][96] bf16 (h 0-63, x 64-71, pad) ; x_T[b][p][32]
//   k_prep_all       : all 4 weight packs in one launch
//   k_flowgen_mfma   : f_T = tanh(25-tap implicit GEMM, K=96); LDS-staged
//   k_flows_mfma     : flows = 25-tap implicit GEMM, K=32           f32
//   k_warp_gemm_gate : 64-px tile (R14 geometry, best measured). Software-
//                      pipelined gather (T14): {issue 2-flow corner loads} ->
//                      {1 i2h tap} -> {consume}, so L2 latency hides under
//                      MFMA. XOR-swizzled LDS; h2h GEMM from LDS; GRU gate.
//   BATCH-PER-XCD: heavy kernels 1D grid, b = id & 7 (validated R12: FETCH
//   145->38 MB)
//
// ws layout:
//   [0)          catT  25,165,824
//   [25,165,824) f_T    8,388,608
//   [33,554,432) flows  5,242,880
//   [38,797,312) xT     8,388,608
//   [63,963,136) packed_ret 122,880
//   [64,086,016) pfg 153,600 | [64,239,616) pfl 25,600 | [64,265,216) pih 110,592
//   end 64,375,808  (proven ws_size >= 134,340,608)

#define HW 16384
#define W_ 128

typedef __attribute__((ext_vector_type(8))) short short8;
typedef __attribute__((ext_vector_type(4))) float f32x4;
typedef __attribute__((ext_vector_type(4))) unsigned int u32x4;

__device__ __forceinline__ float sigmoidf_(float z) { return 1.f / (1.f + expf(-z)); }

__device__ __forceinline__ short bf16bits(float v) {
  __hip_bfloat16 bv = __float2bfloat16(v);
  return (short)*reinterpret_cast<unsigned short*>(&bv);
}
__device__ __forceinline__ unsigned int bf16u(float v) {
  __hip_bfloat16 bv = __float2bfloat16(v);
  return (unsigned int)*reinterpret_cast<unsigned short*>(&bv);
}
__device__ __forceinline__ float bfb2f(short s) {
  union { unsigned int u; float f; } cv;
  cv.u = ((unsigned int)(unsigned short)s) << 16;
  return cv.f;
}

// ---- cat_T[b][p][96] (h,x,0) + x_T[b][p][32] (x,0)
__global__ __launch_bounds__(256) void k_transpose(
    const float* __restrict__ h, const float* __restrict__ x,
    __hip_bfloat16* __restrict__ cat, __hip_bfloat16* __restrict__ xT) {
  const int b = blockIdx.y;
  const int wv = threadIdx.x >> 6, l = threadIdx.x & 63;
  const int p = blockIdx.x * 64 + l;
  const int c0 = wv * 24;
  short8 v[3];
#pragma unroll
  for (int q = 0; q < 3; ++q)
#pragma unroll
    for (int k = 0; k < 8; ++k) {
      int c = c0 + q * 8 + k;
      float val = 0.f;
      if (c < 64)      val = h[((size_t)(b * 64 + c) << 14) + p];
      else if (c < 72) val = x[((size_t)(b * 8 + (c - 64)) << 14) + p];
      v[q][k] = bf16bits(val);
    }
  short8* dst = reinterpret_cast<short8*>(cat + ((size_t)b * HW + p) * 96 + c0);
#pragma unroll
  for (int q = 0; q < 3; ++q) dst[q] = v[q];

  short8 xv;
#pragma unroll
  for (int k = 0; k < 8; ++k)
    xv[k] = (wv == 0) ? bf16bits(x[((size_t)(b * 8 + k) << 14) + p]) : (short)0;
  reinterpret_cast<short8*>(xT + ((size_t)b * HW + p) * 32)[wv] = xv;
}

// ---- all weight preps fused (ranges: fg 76800 | fl 12800 | ret 61440 | ih 55296)
__global__ void k_prep_all(const float* __restrict__ w_i2f,
                           const float* __restrict__ w_h2f,
                           const float* __restrict__ w_flows,
                           const float* __restrict__ w_ret,
                           const float* __restrict__ w_i2h,
                           __hip_bfloat16* __restrict__ pfg,
                           __hip_bfloat16* __restrict__ pfl,
                           __hip_bfloat16* __restrict__ packed,
                           __hip_bfloat16* __restrict__ pih) {
  int t = blockIdx.x * 256 + threadIdx.x;
  if (t < 76800) {
    int i = t & 7, l = (t >> 3) & 63, ot = (t >> 9) & 1, r = t >> 10;
    int ks = r % 3, tap = r / 3;
    int oc = ot * 16 + (l & 15), k = ks * 32 + ((l >> 4) << 3) + i;
    float v = 0.f;
    if (k < 64)      v = w_h2f[(size_t)(oc * 64 + k) * 25 + tap];
    else if (k < 72) v = w_i2f[(size_t)(oc * 8 + (k - 64)) * 25 + tap];
    pfg[t] = __float2bfloat16(v);
    return;
  }
  t -= 76800;
  if (t < 12800) {
    int i = t & 7, l = (t >> 3) & 63, tap = t >> 9;
    int oc = l & 15, k = ((l >> 4) << 3) + i;
    pfl[t] = __float2bfloat16(oc < 10 ? w_flows[(size_t)(oc * 32 + k) * 25 + tap] : 0.f);
    return;
  }
  t -= 12800;
  if (t < 61440) {
    int i = t & 7, l = (t >> 3) & 63, ks = (t >> 9) % 10, mt = t / 5120;
    int m = mt * 16 + (l & 15), k = ks * 32 + ((l >> 4) << 3) + i;
    packed[t] = __float2bfloat16(w_ret[(size_t)m * 320 + k]);
    return;
  }
  t -= 61440;
  if (t < 55296) {
    int i = t & 7, l = (t >> 3) & 63, mt = (t >> 9) % 12, tap = t / 6144;
    int m = mt * 16 + (l & 15), k = ((l >> 4) << 3) + i;
    pih[t] = __float2bfloat16(k < 8 ? w_i2h[(size_t)(m * 8 + k) * 9 + tap] : 0.f);
  }
}

// ---- flowgen: 25-tap implicit GEMM, K=96 (3 staged k-slices). Batch = id&7.
__global__ __launch_bounds__(256) void k_flowgen_mfma(
    const __hip_bfloat16* __restrict__ cat, const __hip_bfloat16* __restrict__ pfg,
    const float* __restrict__ b_i2f, const float* __restrict__ b_h2f,
    __hip_bfloat16* __restrict__ f_T) {
  const int id = blockIdx.x;
  const int b = id & 7, r0 = id >> 3;
  const int y = r0 >> 1, x0 = (r0 & 1) << 6;
  const int wv = threadIdx.x >> 6, l = threadIdx.x & 63;
  const int lr = l & 15, lq = l >> 4;
  const int xa = x0 + wv * 16 + lr;
  const short8* pf = reinterpret_cast<const short8*>(pfg);
  const short8 z8 = {0, 0, 0, 0, 0, 0, 0, 0};

  __shared__ unsigned int s[5 * 68 * 20];  // 27,200 B

  f32x4 acc[2] = {{0.f, 0.f, 0.f, 0.f}, {0.f, 0.f, 0.f, 0.f}};

  for (int ks = 0; ks < 3; ++ks) {
    __syncthreads();
    for (int c = threadIdx.x; c < 1360; c += 256) {
      int px = c >> 2, part = c & 3;
      int r = px / 68, cc = px - r * 68;
      int gy = min(max(y + r - 2, 0), 127);
      int gx = min(max(x0 + cc - 2, 0), 127);
      u32x4 v = *reinterpret_cast<const u32x4*>(
          cat + ((size_t)b * HW + gy * W_ + gx) * 96 + ks * 32 + part * 8);
      *reinterpret_cast<u32x4*>(s + (r * 68 + cc) * 20 + part * 4) = v;
    }
    __syncthreads();
#pragma unroll
    for (int tap = 0; tap < 25; ++tap) {
      const int dy = tap / 5 - 2, dx = tap % 5 - 2;
      const int yy = y + dy, xx = xa + dx;
      const bool ok = ((unsigned)yy < 128u) && ((unsigned)xx < 128u);
      const int cidx = wv * 16 + lr + dx + 2;
      union { u32x4 u; short8 s8; } cv;
      cv.u = *reinterpret_cast<const u32x4*>(s + ((dy + 2) * 68 + cidx) * 20 + lq * 4);
      short8 af = ok ? cv.s8 : z8;
#pragma unroll
      for (int ot = 0; ot < 2; ++ot) {
        short8 bf = pf[(size_t)(((tap * 3 + ks) << 1) + ot) * 64 + l];
        acc[ot] = __builtin_amdgcn_mfma_f32_16x16x32_bf16(af, bf, acc[ot], 0, 0, 0);
      }
    }
  }

  const int pbase = y * W_ + x0 + wv * 16 + lq * 4;
#pragma unroll
  for (int ot = 0; ot < 2; ++ot) {
    const int oc = ot * 16 + lr;
    const float bias = b_i2f[oc] + b_h2f[oc];
#pragma unroll
    for (int r = 0; r < 4; ++r)
      f_T[((size_t)b * HW + pbase + r) * 32 + oc] =
          __float2bfloat16(tanhf(acc[ot][r] + bias));
  }
}

// ---- flows: 25-tap implicit GEMM, K=32. Batch = id&7 (same XCD as producer).
__global__ __launch_bounds__(256) void k_flows_mfma(
    const __hip_bfloat16* __restrict__ f_T, const __hip_bfloat16* __restrict__ pfl,
    const float* __restrict__ b_flows, float* __restrict__ flows) {
  const int id = blockIdx.x;
  const int b = id & 7, r0 = id >> 3;
  const int y = r0 >> 1, x0 = (r0 & 1) << 6;
  const int wv = threadIdx.x >> 6, l = threadIdx.x & 63;
  const int lr = l & 15, lq = l >> 4;
  const int xa = x0 + wv * 16 + lr;
  const short8* ft8 = reinterpret_cast<const short8*>(f_T + (size_t)b * HW * 32);
  const short8* pf = reinterpret_cast<const short8*>(pfl);
  const short8 z8 = {0, 0, 0, 0, 0, 0, 0, 0};

  f32x4 acc = {0.f, 0.f, 0.f, 0.f};

#pragma unroll
  for (int tap = 0; tap < 25; ++tap) {
    const int dy = tap / 5 - 2, dx = tap % 5 - 2;
    const int yy = y + dy, xx = xa + dx;
    const bool ok = ((unsigned)yy < 128u) && ((unsigned)xx < 128u);
    const int yc = min(max(yy, 0), 127), xc = min(max(xx, 0), 127);
    short8 araw = ft8[(size_t)(yc * W_ + xc) * 4 + lq];
    short8 af = ok ? araw : z8;
    short8 bf = pf[tap * 64 + l];
    acc = __builtin_amdgcn_mfma_f32_16x16x32_bf16(af, bf, acc, 0, 0, 0);
  }

  if (lr < 10) {
    const float bb = b_flows[lr];
    const int p = y * W_ + x0 + wv * 16 + lq * 4;
    f32x4 v = {acc[0] + bb, acc[1] + bb, acc[2] + bb, acc[3] + bb};
    *reinterpret_cast<f32x4*>(flows + ((size_t)(b * 10 + lr) << 14) + p) = v;
  }
}

// ---- FUSED warp + h2h GEMM + i2h + gating. 64-px tile (R14 geometry).
// Software pipeline (T14): per pass, {issue 2-flow corner loads} -> {1 i2h tap
// (independent MFMA)} -> {consume: bilinear + swizzled LDS write}; remaining
// taps after. Loads stay in flight across the MFMA cluster.
__global__ __launch_bounds__(256, 3) void k_warp_gemm_gate(
    const __hip_bfloat16* __restrict__ cat, const float* __restrict__ flows,
    const __hip_bfloat16* __restrict__ packed,
    const __hip_bfloat16* __restrict__ pih,
    const __hip_bfloat16* __restrict__ xT,
    const float* __restrict__ h,
    const float* __restrict__ b_i2h, const float* __restrict__ b_ret,
    float* __restrict__ out) {
  const int id = blockIdx.x;
  const int b = id & 7;
  const int p0 = (id >> 3) << 6;
  const int t = threadIdx.x;
  const int wv = t >> 6, l = t & 63;
  const int lr = l & 15, lq = l >> 4;
  const int y = p0 >> 7, x0c = p0 & 127;

  __shared__ unsigned int lds[64 * 160];  // 40,960 B

  // ---- i2h state (accumulators shared with h2h) ----
  f32x4 acc[3][4], accm[4];
#pragma unroll
  for (int g = 0; g < 3; ++g)
#pragma unroll
    for (int q = 0; q < 4; ++q) acc[g][q] = {0.f, 0.f, 0.f, 0.f};
#pragma unroll
  for (int q = 0; q < 4; ++q) accm[q] = {0.f, 0.f, 0.f, 0.f};

  const short8* xb = reinterpret_cast<const short8*>(xT + (size_t)b * HW * 32);
  const short8* pi = reinterpret_cast<const short8*>(pih);
  const short8 z8 = {0, 0, 0, 0, 0, 0, 0, 0};

  auto do_tap = [&](int tap) {
    const int dy = tap / 3 - 1, dx = tap % 3 - 1;
    const int yy = y + dy;
    const bool yok = (unsigned)yy < 128u;
    const int ycl = min(max(yy, 0), 127);
    short8 bf[3];
#pragma unroll
    for (int g = 0; g < 3; ++g) bf[g] = pi[(size_t)(tap * 12 + g * 4 + wv) * 64 + l];
#pragma unroll
    for (int pt = 0; pt < 4; ++pt) {
      const int xx = x0c + pt * 16 + lr + dx;
      const bool ok = yok && ((unsigned)xx < 128u);
      const int xcl = min(max(xx, 0), 127);
      short8 araw = xb[(size_t)(ycl * W_ + xcl) * 4 + lq];
      short8 af = ok ? araw : z8;
      acc[0][pt] = __builtin_amdgcn_mfma_f32_16x16x32_bf16(af, bf[0], acc[0][pt], 0, 0, 0);
      acc[1][pt] = __builtin_amdgcn_mfma_f32_16x16x32_bf16(af, bf[1], acc[1][pt], 0, 0, 0);
      accm[pt]   = __builtin_amdgcn_mfma_f32_16x16x32_bf16(af, bf[2], accm[pt], 0, 0, 0);
    }
  };

  // ---- gather state ----
  const int sub = l >> 3, c8 = l & 7;
  const __hip_bfloat16* cbase = cat + (size_t)b * HW * 96 + c8 * 8;
  float w00[5], w01[5], w10[5], w11[5];
  int o00[5], o01[5], o10[5], o11[5];
  int pxl = 0, p = 0;
  unsigned int sw = 0;
  short8 v00[2], v01[2], v10[2], v11[2];

  auto setup_pass = [&](int pass) {
    pxl = pass * 32 + wv * 8 + sub;
    p = p0 + pxl;
    const int ox = p & 127, oy = p >> 7;
    sw = (unsigned)(pxl & 7);
#pragma unroll
    for (int fl = 0; fl < 5; ++fl) {
      float fx = flows[((size_t)(b * 10 + 2 * fl) << 14) + p];
      float fy = flows[((size_t)(b * 10 + 2 * fl + 1) << 14) + p];
      float px = fminf(fmaxf((float)ox - fx, 0.f), 127.f);
      float py = fminf(fmaxf((float)oy - fy, 0.f), 127.f);
      float x0f = floorf(px), y0f = floorf(py);
      float wx = px - x0f, wy = py - y0f;
      int x0 = (int)x0f, y0 = (int)y0f;
      int x1 = min(x0 + 1, 127), y1 = min(y0 + 1, 127);
      w00[fl] = (1.f - wx) * (1.f - wy); w01[fl] = wx * (1.f - wy);
      w10[fl] = (1.f - wx) * wy;         w11[fl] = wx * wy;
      o00[fl] = (y0 * W_ + x0) * 96; o01[fl] = (y0 * W_ + x1) * 96;
      o10[fl] = (y1 * W_ + x0) * 96; o11[fl] = (y1 * W_ + x1) * 96;
    }
  };

  auto issue = [&](int f0, int nf) {
#pragma unroll
    for (int j = 0; j < 2; ++j)
      if (j < nf) {
        v00[j] = *reinterpret_cast<const short8*>(cbase + o00[f0 + j]);
        v01[j] = *reinterpret_cast<const short8*>(cbase + o01[f0 + j]);
        v10[j] = *reinterpret_cast<const short8*>(cbase + o10[f0 + j]);
        v11[j] = *reinterpret_cast<const short8*>(cbase + o11[f0 + j]);
      }
  };

  auto consume = [&](int f0, int nf) {
#pragma unroll
    for (int j = 0; j < 2; ++j)
      if (j < nf) {
        const int fl = f0 + j;
        u32x4 wvv;
#pragma unroll
        for (int kk = 0; kk < 4; ++kk) {
          float a0 = bfb2f(v00[j][2 * kk]) * w00[fl] + bfb2f(v01[j][2 * kk]) * w01[fl]
                   + bfb2f(v10[j][2 * kk]) * w10[fl] + bfb2f(v11[j][2 * kk]) * w11[fl];
          float a1 = bfb2f(v00[j][2 * kk + 1]) * w00[fl] + bfb2f(v01[j][2 * kk + 1]) * w01[fl]
                   + bfb2f(v10[j][2 * kk + 1]) * w10[fl] + bfb2f(v11[j][2 * kk + 1]) * w11[fl];
          wvv[kk] = bf16u(a0) | (bf16u(a1) << 16);
        }
        const int g0 = fl * 8 + c8;
        *reinterpret_cast<u32x4*>(lds + pxl * 160 + ((unsigned)(g0 ^ sw) << 2)) = wvv;
      }
  };

  // ---- pipelined phase 1 + i2h ----
  setup_pass(0);
  issue(0, 2); do_tap(0); consume(0, 2);
  issue(2, 2); do_tap(1); consume(2, 2);
  issue(4, 1); do_tap(2); consume(4, 1);
  setup_pass(1);
  issue(0, 2); do_tap(3); consume(0, 2);
  issue(2, 2); do_tap(4); consume(2, 2);
  issue(4, 1); do_tap(5); consume(4, 1);
  do_tap(6); do_tap(7); do_tap(8);

  __syncthreads();

  // ---- h2h GEMM: A-fragments from swizzled LDS ----
  const short8* bp0 = reinterpret_cast<const short8*>(packed) + (size_t)wv * 640 + l;
  for (int ks = 0; ks < 10; ++ks) {
    short8 af[4];
#pragma unroll
    for (int pt = 0; pt < 4; ++pt) {
      const int row = pt * 16 + lr;
      union { u32x4 u; short8 s; } cv;
      cv.u = *reinterpret_cast<const u32x4*>(
          lds + row * 160 + ((unsigned)(((ks << 2) + lq) ^ (row & 7)) << 2));
      af[pt] = cv.s;
    }
    short8 bf[3];
#pragma unroll
    for (int g = 0; g < 3; ++g) bf[g] = bp0[g * 2560 + ks * 64];
#pragma unroll
    for (int g = 0; g < 3; ++g)
#pragma unroll
      for (int pt = 0; pt < 4; ++pt)
        acc[g][pt] = __builtin_amdgcn_mfma_f32_16x16x32_bf16(af[pt], bf[g],
                                                             acc[g][pt], 0, 0, 0);
  }

  const int c = wv * 16 + lr;
  const float bir = b_i2h[c], biu = b_i2h[64 + c], bim = b_i2h[128 + c];
  const float brr = b_ret[c], bru = b_ret[64 + c], brm = b_ret[128 + c];
  const float* hb = h + ((size_t)(b * 64 + c) << 14);
  float* ob = out + ((size_t)(b * 64 + c) << 14);
#pragma unroll
  for (int pt = 0; pt < 4; ++pt) {
#pragma unroll
    for (int r = 0; r < 4; ++r) {
      const int pixel = p0 + pt * 16 + lq * 4 + r;
      float rg = sigmoidf_(acc[0][pt][r] + bir + brr);
      float ug = sigmoidf_(acc[1][pt][r] + biu + bru);
      float mg = tanhf((accm[pt][r] + bim) + rg * (acc[2][pt][r] + brm));
      ob[pixel] = ug * hb[pixel] + (1.f - ug) * mg;
    }
  }
}

extern "C" void kernel_launch(void* const* d_in, const int* in_sizes, int n_in,
                              void* d_out, int out_size, void* d_ws, size_t ws_size,
                              hipStream_t stream) {
  const float* x       = (const float*)d_in[0];
  const float* h       = (const float*)d_in[1];
  const float* w_i2f   = (const float*)d_in[2];
  const float* b_i2f   = (const float*)d_in[3];
  const float* w_h2f   = (const float*)d_in[4];
  const float* b_h2f   = (const float*)d_in[5];
  const float* w_flows = (const float*)d_in[6];
  const float* b_flows = (const float*)d_in[7];
  const float* w_i2h   = (const float*)d_in[8];
  const float* b_i2h   = (const float*)d_in[9];
  const float* w_ret   = (const float*)d_in[10];
  const float* b_ret   = (const float*)d_in[11];
  float* out           = (float*)d_out;
  char* ws = (char*)d_ws;

  __hip_bfloat16* catT   = (__hip_bfloat16*)(ws);             // 25,165,824
  __hip_bfloat16* f_T    = (__hip_bfloat16*)(ws + 25165824);  // 8,388,608
  float* flows           = (float*)(ws + 33554432);           // 5,242,880
  __hip_bfloat16* xT     = (__hip_bfloat16*)(ws + 38797312);  // 8,388,608
  __hip_bfloat16* packed = (__hip_bfloat16*)(ws + 63963136);  // 122,880
  __hip_bfloat16* pfg    = (__hip_bfloat16*)(ws + 64086016);  // 153,600
  __hip_bfloat16* pfl    = (__hip_bfloat16*)(ws + 64239616);  // 25,600
  __hip_bfloat16* pih    = (__hip_bfloat16*)(ws + 64265216);  // 110,592

  k_transpose<<<dim3(256, 8), 256, 0, stream>>>(h, x, catT, xT);
  k_prep_all<<<806, 256, 0, stream>>>(w_i2f, w_h2f, w_flows, w_ret, w_i2h,
                                      pfg, pfl, packed, pih);

  k_flowgen_mfma<<<2048, 256, 0, stream>>>(catT, pfg, b_i2f, b_h2f, f_T);
  k_flows_mfma<<<2048, 256, 0, stream>>>(f_T, pfl, b_flows, flows);

  k_warp_gemm_gate<<<2048, 256, 0, stream>>>(catT, flows, packed, pih, xT,
                                             h, b_i2h, b_ret, out);
}

// Round 17
// 165.051 us; speedup vs baseline: 1.0836x; 1.0815x over previous
//
#include <hip/hip_runtime.h>
#include <hip/hip_bf16.h>

// TrajGRU cell, B=8, Cin=8, Ch=64, H=W=128, L=5. Inputs f32, OUTPUT f32.
// == R14 configuration (best measured: 165 µs) ==
//   k_transpose      : cat_T[b][p][96] bf16 (h 0-63, x 64-71, pad) ; x_T[b][p][32]
//   k_prep_all       : all 4 weight packs in one launch
//   k_flowgen_mfma   : f_T = tanh(25-tap implicit GEMM, K=96); LDS-staged
//   k_flows_mfma     : flows = 25-tap implicit GEMM, K=32           f32
//   k_warp_gemm_gate : 64-px tile; channel-octet gather (16 lines/instr,
//                      unique-line minimum); grouped loads (MLP); XOR-swizzled
//                      LDS; i2h MFMA overlaps barrier; h2h GEMM; GRU gate
//   BATCH-PER-XCD: heavy kernels 1D grid, b = id & 7 (validated R12: FETCH
//   145->38 MB). Known-limit note: remaining kwgg gap is exposed L2-gather
//   latency; R15 (occupancy) and R16 (src-level pipelining) both regressed.
//
// ws layout:
//   [0)          catT  25,165,824
//   [25,165,824) f_T    8,388,608
//   [33,554,432) flows  5,242,880
//   [38,797,312) xT     8,388,608
//   [63,963,136) packed_ret 122,880
//   [64,086,016) pfg 153,600 | [64,239,616) pfl 25,600 | [64,265,216) pih 110,592
//   end 64,375,808  (proven ws_size >= 134,340,608)

#define HW 16384
#define W_ 128

typedef __attribute__((ext_vector_type(8))) short short8;
typedef __attribute__((ext_vector_type(4))) float f32x4;
typedef __attribute__((ext_vector_type(4))) unsigned int u32x4;

__device__ __forceinline__ float sigmoidf_(float z) { return 1.f / (1.f + expf(-z)); }

__device__ __forceinline__ short bf16bits(float v) {
  __hip_bfloat16 bv = __float2bfloat16(v);
  return (short)*reinterpret_cast<unsigned short*>(&bv);
}
__device__ __forceinline__ unsigned int bf16u(float v) {
  __hip_bfloat16 bv = __float2bfloat16(v);
  return (unsigned int)*reinterpret_cast<unsigned short*>(&bv);
}
__device__ __forceinline__ float bfb2f(short s) {
  union { unsigned int u; float f; } cv;
  cv.u = ((unsigned int)(unsigned short)s) << 16;
  return cv.f;
}

// ---- cat_T[b][p][96] (h,x,0) + x_T[b][p][32] (x,0)
__global__ __launch_bounds__(256) void k_transpose(
    const float* __restrict__ h, const float* __restrict__ x,
    __hip_bfloat16* __restrict__ cat, __hip_bfloat16* __restrict__ xT) {
  const int b = blockIdx.y;
  const int wv = threadIdx.x >> 6, l = threadIdx.x & 63;
  const int p = blockIdx.x * 64 + l;
  const int c0 = wv * 24;
  short8 v[3];
#pragma unroll
  for (int q = 0; q < 3; ++q)
#pragma unroll
    for (int k = 0; k < 8; ++k) {
      int c = c0 + q * 8 + k;
      float val = 0.f;
      if (c < 64)      val = h[((size_t)(b * 64 + c) << 14) + p];
      else if (c < 72) val = x[((size_t)(b * 8 + (c - 64)) << 14) + p];
      v[q][k] = bf16bits(val);
    }
  short8* dst = reinterpret_cast<short8*>(cat + ((size_t)b * HW + p) * 96 + c0);
#pragma unroll
  for (int q = 0; q < 3; ++q) dst[q] = v[q];

  short8 xv;
#pragma unroll
  for (int k = 0; k < 8; ++k)
    xv[k] = (wv == 0) ? bf16bits(x[((size_t)(b * 8 + k) << 14) + p]) : (short)0;
  reinterpret_cast<short8*>(xT + ((size_t)b * HW + p) * 32)[wv] = xv;
}

// ---- all weight preps fused (ranges: fg 76800 | fl 12800 | ret 61440 | ih 55296)
__global__ void k_prep_all(const float* __restrict__ w_i2f,
                           const float* __restrict__ w_h2f,
                           const float* __restrict__ w_flows,
                           const float* __restrict__ w_ret,
                           const float* __restrict__ w_i2h,
                           __hip_bfloat16* __restrict__ pfg,
                           __hip_bfloat16* __restrict__ pfl,
                           __hip_bfloat16* __restrict__ packed,
                           __hip_bfloat16* __restrict__ pih) {
  int t = blockIdx.x * 256 + threadIdx.x;
  if (t < 76800) {
    int i = t & 7, l = (t >> 3) & 63, ot = (t >> 9) & 1, r = t >> 10;
    int ks = r % 3, tap = r / 3;
    int oc = ot * 16 + (l & 15), k = ks * 32 + ((l >> 4) << 3) + i;
    float v = 0.f;
    if (k < 64)      v = w_h2f[(size_t)(oc * 64 + k) * 25 + tap];
    else if (k < 72) v = w_i2f[(size_t)(oc * 8 + (k - 64)) * 25 + tap];
    pfg[t] = __float2bfloat16(v);
    return;
  }
  t -= 76800;
  if (t < 12800) {
    int i = t & 7, l = (t >> 3) & 63, tap = t >> 9;
    int oc = l & 15, k = ((l >> 4) << 3) + i;
    pfl[t] = __float2bfloat16(oc < 10 ? w_flows[(size_t)(oc * 32 + k) * 25 + tap] : 0.f);
    return;
  }
  t -= 12800;
  if (t < 61440) {
    int i = t & 7, l = (t >> 3) & 63, ks = (t >> 9) % 10, mt = t / 5120;
    int m = mt * 16 + (l & 15), k = ks * 32 + ((l >> 4) << 3) + i;
    packed[t] = __float2bfloat16(w_ret[(size_t)m * 320 + k]);
    return;
  }
  t -= 61440;
  if (t < 55296) {
    int i = t & 7, l = (t >> 3) & 63, mt = (t >> 9) % 12, tap = t / 6144;
    int m = mt * 16 + (l & 15), k = ((l >> 4) << 3) + i;
    pih[t] = __float2bfloat16(k < 8 ? w_i2h[(size_t)(m * 8 + k) * 9 + tap] : 0.f);
  }
}

// ---- flowgen: 25-tap implicit GEMM, K=96 (3 staged k-slices). Batch = id&7.
__global__ __launch_bounds__(256) void k_flowgen_mfma(
    const __hip_bfloat16* __restrict__ cat, const __hip_bfloat16* __restrict__ pfg,
    const float* __restrict__ b_i2f, const float* __restrict__ b_h2f,
    __hip_bfloat16* __restrict__ f_T) {
  const int id = blockIdx.x;
  const int b = id & 7, r0 = id >> 3;
  const int y = r0 >> 1, x0 = (r0 & 1) << 6;
  const int wv = threadIdx.x >> 6, l = threadIdx.x & 63;
  const int lr = l & 15, lq = l >> 4;
  const int xa = x0 + wv * 16 + lr;
  const short8* pf = reinterpret_cast<const short8*>(pfg);
  const short8 z8 = {0, 0, 0, 0, 0, 0, 0, 0};

  __shared__ unsigned int s[5 * 68 * 20];  // 27,200 B

  f32x4 acc[2] = {{0.f, 0.f, 0.f, 0.f}, {0.f, 0.f, 0.f, 0.f}};

  for (int ks = 0; ks < 3; ++ks) {
    __syncthreads();
    for (int c = threadIdx.x; c < 1360; c += 256) {
      int px = c >> 2, part = c & 3;
      int r = px / 68, cc = px - r * 68;
      int gy = min(max(y + r - 2, 0), 127);
      int gx = min(max(x0 + cc - 2, 0), 127);
      u32x4 v = *reinterpret_cast<const u32x4*>(
          cat + ((size_t)b * HW + gy * W_ + gx) * 96 + ks * 32 + part * 8);
      *reinterpret_cast<u32x4*>(s + (r * 68 + cc) * 20 + part * 4) = v;
    }
    __syncthreads();
#pragma unroll
    for (int tap = 0; tap < 25; ++tap) {
      const int dy = tap / 5 - 2, dx = tap % 5 - 2;
      const int yy = y + dy, xx = xa + dx;
      const bool ok = ((unsigned)yy < 128u) && ((unsigned)xx < 128u);
      const int cidx = wv * 16 + lr + dx + 2;
      union { u32x4 u; short8 s8; } cv;
      cv.u = *reinterpret_cast<const u32x4*>(s + ((dy + 2) * 68 + cidx) * 20 + lq * 4);
      short8 af = ok ? cv.s8 : z8;
#pragma unroll
      for (int ot = 0; ot < 2; ++ot) {
        short8 bf = pf[(size_t)(((tap * 3 + ks) << 1) + ot) * 64 + l];
        acc[ot] = __builtin_amdgcn_mfma_f32_16x16x32_bf16(af, bf, acc[ot], 0, 0, 0);
      }
    }
  }

  const int pbase = y * W_ + x0 + wv * 16 + lq * 4;
#pragma unroll
  for (int ot = 0; ot < 2; ++ot) {
    const int oc = ot * 16 + lr;
    const float bias = b_i2f[oc] + b_h2f[oc];
#pragma unroll
    for (int r = 0; r < 4; ++r)
      f_T[((size_t)b * HW + pbase + r) * 32 + oc] =
          __float2bfloat16(tanhf(acc[ot][r] + bias));
  }
}

// ---- flows: 25-tap implicit GEMM, K=32. Batch = id&7 (same XCD as producer).
__global__ __launch_bounds__(256) void k_flows_mfma(
    const __hip_bfloat16* __restrict__ f_T, const __hip_bfloat16* __restrict__ pfl,
    const float* __restrict__ b_flows, float* __restrict__ flows) {
  const int id = blockIdx.x;
  const int b = id & 7, r0 = id >> 3;
  const int y = r0 >> 1, x0 = (r0 & 1) << 6;
  const int wv = threadIdx.x >> 6, l = threadIdx.x & 63;
  const int lr = l & 15, lq = l >> 4;
  const int xa = x0 + wv * 16 + lr;
  const short8* ft8 = reinterpret_cast<const short8*>(f_T + (size_t)b * HW * 32);
  const short8* pf = reinterpret_cast<const short8*>(pfl);
  const short8 z8 = {0, 0, 0, 0, 0, 0, 0, 0};

  f32x4 acc = {0.f, 0.f, 0.f, 0.f};

#pragma unroll
  for (int tap = 0; tap < 25; ++tap) {
    const int dy = tap / 5 - 2, dx = tap % 5 - 2;
    const int yy = y + dy, xx = xa + dx;
    const bool ok = ((unsigned)yy < 128u) && ((unsigned)xx < 128u);
    const int yc = min(max(yy, 0), 127), xc = min(max(xx, 0), 127);
    short8 araw = ft8[(size_t)(yc * W_ + xc) * 4 + lq];
    short8 af = ok ? araw : z8;
    short8 bf = pf[tap * 64 + l];
    acc = __builtin_amdgcn_mfma_f32_16x16x32_bf16(af, bf, acc, 0, 0, 0);
  }

  if (lr < 10) {
    const float bb = b_flows[lr];
    const int p = y * W_ + x0 + wv * 16 + lq * 4;
    f32x4 v = {acc[0] + bb, acc[1] + bb, acc[2] + bb, acc[3] + bb};
    *reinterpret_cast<f32x4*>(flows + ((size_t)(b * 10 + lr) << 14) + p) = v;
  }
}

// ---- FUSED warp + h2h GEMM + i2h + gating. 64-px tile, batch = id&7.
// Phase 1 lane map: sub = l>>3 -> pixel, c8 = l&7 -> channel octet (16 lines
// per gather instr). MLP: per pass, ALL flow loads -> ALL addresses -> ALL 20
// corner loads -> bilinear + swizzled LDS writes.
__global__ __launch_bounds__(256, 4) void k_warp_gemm_gate(
    const __hip_bfloat16* __restrict__ cat, const float* __restrict__ flows,
    const __hip_bfloat16* __restrict__ packed,
    const __hip_bfloat16* __restrict__ pih,
    const __hip_bfloat16* __restrict__ xT,
    const float* __restrict__ h,
    const float* __restrict__ b_i2h, const float* __restrict__ b_ret,
    float* __restrict__ out) {
  const int id = blockIdx.x;
  const int b = id & 7;
  const int p0 = (id >> 3) << 6;
  const int t = threadIdx.x;
  const int wv = t >> 6, l = t & 63;

  __shared__ unsigned int lds[64 * 160];  // 40,960 B

  {  // phase 1: channel-octet gather with grouped loads (max MLP)
    const int sub = l >> 3, c8 = l & 7;
    const __hip_bfloat16* cbase = cat + (size_t)b * HW * 96 + c8 * 8;
#pragma unroll
    for (int pass = 0; pass < 2; ++pass) {
      const int pxl = pass * 32 + wv * 8 + sub;
      const int p = p0 + pxl;
      const int ox = p & 127, oy = p >> 7;
      const unsigned int sw = (unsigned)(pxl & 7);

      float fx[5], fy[5];
#pragma unroll
      for (int fl = 0; fl < 5; ++fl) {
        fx[fl] = flows[((size_t)(b * 10 + 2 * fl) << 14) + p];
        fy[fl] = flows[((size_t)(b * 10 + 2 * fl + 1) << 14) + p];
      }
      float w00[5], w01[5], w10[5], w11[5];
      const short8 *q00[5], *q01[5], *q10[5], *q11[5];
#pragma unroll
      for (int fl = 0; fl < 5; ++fl) {
        float px = fminf(fmaxf((float)ox - fx[fl], 0.f), 127.f);
        float py = fminf(fmaxf((float)oy - fy[fl], 0.f), 127.f);
        float x0f = floorf(px), y0f = floorf(py);
        float wx = px - x0f, wy = py - y0f;
        int x0 = (int)x0f, y0 = (int)y0f;
        int x1 = min(x0 + 1, 127), y1 = min(y0 + 1, 127);
        w00[fl] = (1.f - wx) * (1.f - wy); w01[fl] = wx * (1.f - wy);
        w10[fl] = (1.f - wx) * wy;         w11[fl] = wx * wy;
        q00[fl] = reinterpret_cast<const short8*>(cbase + (size_t)(y0 * W_ + x0) * 96);
        q01[fl] = reinterpret_cast<const short8*>(cbase + (size_t)(y0 * W_ + x1) * 96);
        q10[fl] = reinterpret_cast<const short8*>(cbase + (size_t)(y1 * W_ + x0) * 96);
        q11[fl] = reinterpret_cast<const short8*>(cbase + (size_t)(y1 * W_ + x1) * 96);
      }
      short8 v00[5], v01[5], v10[5], v11[5];
#pragma unroll
      for (int fl = 0; fl < 5; ++fl) {
        v00[fl] = *q00[fl]; v01[fl] = *q01[fl];
        v10[fl] = *q10[fl]; v11[fl] = *q11[fl];
      }
#pragma unroll
      for (int fl = 0; fl < 5; ++fl) {
        u32x4 wvv;
#pragma unroll
        for (int kk = 0; kk < 4; ++kk) {
          float a0 = bfb2f(v00[fl][2 * kk]) * w00[fl] + bfb2f(v01[fl][2 * kk]) * w01[fl]
                   + bfb2f(v10[fl][2 * kk]) * w10[fl] + bfb2f(v11[fl][2 * kk]) * w11[fl];
          float a1 = bfb2f(v00[fl][2 * kk + 1]) * w00[fl] + bfb2f(v01[fl][2 * kk + 1]) * w01[fl]
                   + bfb2f(v10[fl][2 * kk + 1]) * w10[fl] + bfb2f(v11[fl][2 * kk + 1]) * w11[fl];
          wvv[kk] = bf16u(a0) | (bf16u(a1) << 16);
        }
        const int g0 = fl * 8 + c8;  // 16B chunk index (0..39)
        *reinterpret_cast<u32x4*>(lds + pxl * 160 + ((unsigned)(g0 ^ sw) << 2)) = wvv;
      }
    }
  }

  // i2h: 9-tap implicit GEMM over x_T (no LDS use — overlaps the barrier wait)
  const int y = p0 >> 7, x0 = p0 & 127;
  const int lr = l & 15, lq = l >> 4;

  f32x4 acc[3][4], accm[4];
#pragma unroll
  for (int g = 0; g < 3; ++g)
#pragma unroll
    for (int q = 0; q < 4; ++q) acc[g][q] = {0.f, 0.f, 0.f, 0.f};
#pragma unroll
  for (int q = 0; q < 4; ++q) accm[q] = {0.f, 0.f, 0.f, 0.f};

  {
    const short8* xb = reinterpret_cast<const short8*>(xT + (size_t)b * HW * 32);
    const short8* pi = reinterpret_cast<const short8*>(pih);
    const short8 z8 = {0, 0, 0, 0, 0, 0, 0, 0};
#pragma unroll
    for (int tap = 0; tap < 9; ++tap) {
      const int dy = tap / 3 - 1, dx = tap % 3 - 1;
      const int yy = y + dy;
      const bool yok = (unsigned)yy < 128u;
      const int ycl = min(max(yy, 0), 127);
      short8 bf[3];
#pragma unroll
      for (int g = 0; g < 3; ++g) bf[g] = pi[(size_t)(tap * 12 + g * 4 + wv) * 64 + l];
#pragma unroll
      for (int pt = 0; pt < 4; ++pt) {
        const int xx = x0 + pt * 16 + lr + dx;
        const bool ok = yok && ((unsigned)xx < 128u);
        const int xcl = min(max(xx, 0), 127);
        short8 araw = xb[(size_t)(ycl * W_ + xcl) * 4 + lq];
        short8 af = ok ? araw : z8;
        acc[0][pt] = __builtin_amdgcn_mfma_f32_16x16x32_bf16(af, bf[0], acc[0][pt], 0, 0, 0);
        acc[1][pt] = __builtin_amdgcn_mfma_f32_16x16x32_bf16(af, bf[1], acc[1][pt], 0, 0, 0);
        accm[pt]   = __builtin_amdgcn_mfma_f32_16x16x32_bf16(af, bf[2], accm[pt], 0, 0, 0);
      }
    }
  }

  __syncthreads();

  // h2h GEMM: A-fragments from swizzled LDS
  const short8* bp0 = reinterpret_cast<const short8*>(packed) + (size_t)wv * 640 + l;
  for (int ks = 0; ks < 10; ++ks) {
    short8 af[4];
#pragma unroll
    for (int pt = 0; pt < 4; ++pt) {
      const int row = pt * 16 + lr;
      union { u32x4 u; short8 s; } cv;
      cv.u = *reinterpret_cast<const u32x4*>(
          lds + row * 160 + ((unsigned)(((ks << 2) + lq) ^ (row & 7)) << 2));
      af[pt] = cv.s;
    }
    short8 bf[3];
#pragma unroll
    for (int g = 0; g < 3; ++g) bf[g] = bp0[g * 2560 + ks * 64];
#pragma unroll
    for (int g = 0; g < 3; ++g)
#pragma unroll
      for (int pt = 0; pt < 4; ++pt)
        acc[g][pt] = __builtin_amdgcn_mfma_f32_16x16x32_bf16(af[pt], bf[g],
                                                             acc[g][pt], 0, 0, 0);
  }

  const int c = wv * 16 + lr;
  const float bir = b_i2h[c], biu = b_i2h[64 + c], bim = b_i2h[128 + c];
  const float brr = b_ret[c], bru = b_ret[64 + c], brm = b_ret[128 + c];
  const float* hb = h + ((size_t)(b * 64 + c) << 14);
  float* ob = out + ((size_t)(b * 64 + c) << 14);
#pragma unroll
  for (int pt = 0; pt < 4; ++pt) {
#pragma unroll
    for (int r = 0; r < 4; ++r) {
      const int pixel = p0 + pt * 16 + lq * 4 + r;
      float rg = sigmoidf_(acc[0][pt][r] + bir + brr);
      float ug = sigmoidf_(acc[1][pt][r] + biu + bru);
      float mg = tanhf((accm[pt][r] + bim) + rg * (acc[2][pt][r] + brm));
      ob[pixel] = ug * hb[pixel] + (1.f - ug) * mg;
    }
  }
}

extern "C" void kernel_launch(void* const* d_in, const int* in_sizes, int n_in,
                              void* d_out, int out_size, void* d_ws, size_t ws_size,
                              hipStream_t stream) {
  const float* x       = (const float*)d_in[0];
  const float* h       = (const float*)d_in[1];
  const float* w_i2f   = (const float*)d_in[2];
  const float* b_i2f   = (const float*)d_in[3];
  const float* w_h2f   = (const float*)d_in[4];
  const float* b_h2f   = (const float*)d_in[5];
  const float* w_flows = (const float*)d_in[6];
  const float* b_flows = (const float*)d_in[7];
  const float* w_i2h   = (const float*)d_in[8];
  const float* b_i2h   = (const float*)d_in[9];
  const float* w_ret   = (const float*)d_in[10];
  const float* b_ret   = (const float*)d_in[11];
  float* out           = (float*)d_out;
  char* ws = (char*)d_ws;

  __hip_bfloat16* catT   = (__hip_bfloat16*)(ws);             // 25,165,824
  __hip_bfloat16* f_T    = (__hip_bfloat16*)(ws + 25165824);  // 8,388,608
  float* flows           = (float*)(ws + 33554432);           // 5,242,880
  __hip_bfloat16* xT     = (__hip_bfloat16*)(ws + 38797312);  // 8,388,608
  __hip_bfloat16* packed = (__hip_bfloat16*)(ws + 63963136);  // 122,880
  __hip_bfloat16* pfg    = (__hip_bfloat16*)(ws + 64086016);  // 153,600
  __hip_bfloat16* pfl    = (__hip_bfloat16*)(ws + 64239616);  // 25,600
  __hip_bfloat16* pih    = (__hip_bfloat16*)(ws + 64265216);  // 110,592

  k_transpose<<<dim3(256, 8), 256, 0, stream>>>(h, x, catT, xT);
  k_prep_all<<<806, 256, 0, stream>>>(w_i2f, w_h2f, w_flows, w_ret, w_i2h,
                                      pfg, pfl, packed, pih);

  k_flowgen_mfma<<<2048, 256, 0, stream>>>(catT, pfg, b_i2f, b_h2f, f_T);
  k_flows_mfma<<<2048, 256, 0, stream>>>(f_T, pfl, b_flows, flows);

  k_warp_gemm_gate<<<2048, 256, 0, stream>>>(catT, flows, packed, pih, xT,
                                             h, b_i2h, b_ret, out);
}